// Round 8
// baseline (399.495 us; speedup 1.0000x reference)
//
#include <hip/hip_runtime.h>

#define NN 100000
#define DD 256
#define SCAN_BLK 1024

typedef unsigned int uint;
typedef unsigned short ushort;
typedef __attribute__((ext_vector_type(8))) short bfx8;
typedef __attribute__((ext_vector_type(4))) float fx4;

__device__ __forceinline__ ushort f2bf(float f) {  // RNE
    uint u = __float_as_uint(f);
    u += 0x7fff + ((u >> 16) & 1);
    return (ushort)(u >> 16);
}

// ---------------- degree / norm ----------------
__global__ __launch_bounds__(256) void k_init_deg(int* __restrict__ dego,
                                                  int* __restrict__ degi) {
    int i = blockIdx.x * 256 + threadIdx.x;
    if (i < NN) { dego[i] = 1; degi[i] = 1; }  // self-loop contributes 1
}

__global__ __launch_bounds__(256) void k_count(const int* __restrict__ src,
                                               const int* __restrict__ dst, int E,
                                               int* __restrict__ dego,
                                               int* __restrict__ degi) {
    int e = blockIdx.x * 256 + threadIdx.x;
    if (e < E) {
        atomicAdd(&dego[src[e]], 1);
        atomicAdd(&degi[dst[e]], 1);
    }
}

__global__ __launch_bounds__(256) void k_norm(const int* __restrict__ dego,
                                              const int* __restrict__ degi,
                                              float* __restrict__ ns,
                                              float* __restrict__ nd) {
    int i = blockIdx.x * 256 + threadIdx.x;
    if (i < NN) {
        ns[i] = rsqrtf((float)dego[i]);
        nd[i] = rsqrtf((float)degi[i]);
    }
}

// ---------------- CSR build (scan by dst) ----------------
__device__ __forceinline__ int block_scan_inc(int v, int* sm) {
    int t = threadIdx.x;
    sm[t] = v;
    __syncthreads();
    for (int o = 1; o < SCAN_BLK; o <<= 1) {
        int x = (t >= o) ? sm[t - o] : 0;
        __syncthreads();
        sm[t] += x;
        __syncthreads();
    }
    return sm[t];
}

__global__ __launch_bounds__(SCAN_BLK) void k_scan1(const int* __restrict__ degi,
                                                    int* __restrict__ partials) {
    __shared__ int sm[SCAN_BLK];
    int i = blockIdx.x * SCAN_BLK + threadIdx.x;
    int v = (i < NN) ? (degi[i] - 1) : 0;  // real in-edges only
    block_scan_inc(v, sm);
    if (threadIdx.x == 0) partials[blockIdx.x] = sm[SCAN_BLK - 1];
}

__global__ __launch_bounds__(128) void k_scan2(int* __restrict__ partials, int nb) {
    __shared__ int sm[128];
    int t = threadIdx.x;
    int v = (t < nb) ? partials[t] : 0;
    sm[t] = v;
    __syncthreads();
    for (int o = 1; o < 128; o <<= 1) {
        int x = (t >= o) ? sm[t - o] : 0;
        __syncthreads();
        sm[t] += x;
        __syncthreads();
    }
    if (t < nb) partials[t] = sm[t] - v;  // exclusive
}

__global__ __launch_bounds__(SCAN_BLK) void k_scan3(const int* __restrict__ degi,
                                                    const int* __restrict__ partials,
                                                    int* __restrict__ rowptr,
                                                    int* __restrict__ cursor) {
    __shared__ int sm[SCAN_BLK];
    int i = blockIdx.x * SCAN_BLK + threadIdx.x;
    int v = (i < NN) ? (degi[i] - 1) : 0;
    int incl = block_scan_inc(v, sm);
    int excl = partials[blockIdx.x] + incl - v;
    if (i <= NN) rowptr[i] = excl;   // rowptr[NN] = E
    if (i < NN) cursor[i] = excl;
}

__global__ __launch_bounds__(256) void k_fill(const int* __restrict__ src,
                                              const int* __restrict__ dst, int E,
                                              int* __restrict__ cursor,
                                              int* __restrict__ eidx) {
    int e = blockIdx.x * 256 + threadIdx.x;
    if (e < E) {
        int d = dst[e];
        int p = atomicAdd(&cursor[d], 1);
        eidx[p] = src[e];
    }
}

// Wt[n][k] = bf16(W[k][n])  (transposed so GEMM B-frags read k-contiguous)
__global__ __launch_bounds__(256) void k_convW(const float* __restrict__ W,
                                               ushort* __restrict__ Wt) {
    int n = blockIdx.x, k = threadIdx.x;
    Wt[n * DD + k] = f2bf(W[(size_t)k * DD + n]);
}

// ---------------- MFMA GEMM: H = A @ Wt^T (layer 1) ----------------
// Tile 128x256 (A read once), BK=64, 512 threads (8 waves, 2x4 grid), wave
// tile 64x64. A through LDS (dbuf 32 KB); B from global (Wt L2-resident).
template <bool FP32A>
__global__ __launch_bounds__(512, 4) void k_mfgemm(const void* __restrict__ Av,
                                                   const float* __restrict__ nrm,
                                                   const ushort* __restrict__ Wt,
                                                   ushort* __restrict__ H) {
    __shared__ uint4 atq[2][128 * 8];  // A tile [128 r][8 chunks of 16B], dbuf
    int t = threadIdx.x;
    int brow = blockIdx.x * 128;
    int lane = t & 63, w = t >> 6;
    int wr = w >> 2, wc = w & 3;       // wave grid 2x4
    int lg = lane >> 4, lr = lane & 15;

    int sr = t >> 3, sc = t & 7;
    int rows_[2];
    float ns_[2];
#pragma unroll
    for (int i = 0; i < 2; ++i) {
        int r = brow + sr + i * 64;
        if (r >= NN) r = NN - 1;  // tail clamp (results discarded on store)
        rows_[i] = r;
        if (FP32A) ns_[i] = nrm[r];
    }

    const uint4* wb[4];
#pragma unroll
    for (int ni = 0; ni < 4; ++ni)
        wb[ni] = (const uint4*)(Wt + (size_t)(wc * 64 + ni * 16 + lr) * DD);

    fx4 acc[4][4];
#pragma unroll
    for (int mi = 0; mi < 4; ++mi)
#pragma unroll
        for (int ni = 0; ni < 4; ++ni)
            acc[mi][ni] = (fx4){0.f, 0.f, 0.f, 0.f};

    uint4 sva[2];
    float4 svf[2][2];

    auto ldA = [&](int ks) {
        if (FP32A) {
            const float* X = (const float*)Av;
#pragma unroll
            for (int i = 0; i < 2; ++i) {
                const float4* p =
                    (const float4*)(X + (size_t)rows_[i] * DD + ks * 64 + sc * 8);
                svf[i][0] = p[0];
                svf[i][1] = p[1];
            }
        } else {
            const ushort* A = (const ushort*)Av;
#pragma unroll
            for (int i = 0; i < 2; ++i)
                sva[i] = *(const uint4*)(A + (size_t)rows_[i] * DD + ks * 64 + sc * 8);
        }
    };
    auto wrA = [&](int buf) {
#pragma unroll
        for (int i = 0; i < 2; ++i) {
            int r = sr + i * 64;
            uint4 u;
            if (FP32A) {
                float s = ns_[i];
                float4 a = svf[i][0], b = svf[i][1];
                u.x = (uint)f2bf(a.x * s) | ((uint)f2bf(a.y * s) << 16);
                u.y = (uint)f2bf(a.z * s) | ((uint)f2bf(a.w * s) << 16);
                u.z = (uint)f2bf(b.x * s) | ((uint)f2bf(b.y * s) << 16);
                u.w = (uint)f2bf(b.z * s) | ((uint)f2bf(b.w * s) << 16);
            } else {
                u = sva[i];
            }
            atq[buf][r * 8 + (sc ^ (r & 7))] = u;
        }
    };

    ldA(0);
    wrA(0);
    __syncthreads();

    int buf = 0;
#pragma unroll
    for (int ks = 0; ks < 4; ++ks) {
        if (ks < 3) ldA(ks + 1);
#pragma unroll
        for (int kk = 0; kk < 2; ++kk) {
            bfx8 bfr[4], af[4];
#pragma unroll
            for (int ni = 0; ni < 4; ++ni)
                bfr[ni] = *(const bfx8*)&wb[ni][ks * 8 + kk * 4 + lg];
#pragma unroll
            for (int mi = 0; mi < 4; ++mi) {
                int r = wr * 64 + mi * 16 + lr;
                int c = kk * 4 + lg;
                af[mi] = *(const bfx8*)&atq[buf][r * 8 + (c ^ (r & 7))];
            }
#pragma unroll
            for (int mi = 0; mi < 4; ++mi)
#pragma unroll
                for (int ni = 0; ni < 4; ++ni)
                    acc[mi][ni] = __builtin_amdgcn_mfma_f32_16x16x32_bf16(
                        af[mi], bfr[ni], acc[mi][ni], 0, 0, 0);
        }
        if (ks < 3) wrA(buf ^ 1);
        __syncthreads();
        buf ^= 1;
    }

#pragma unroll
    for (int mi = 0; mi < 4; ++mi) {
        int rbase = brow + wr * 64 + mi * 16 + lg * 4;
#pragma unroll
        for (int ni = 0; ni < 4; ++ni) {
            int col = wc * 64 + ni * 16 + lr;
#pragma unroll
            for (int j = 0; j < 4; ++j) {
                int row = rbase + j;
                if (row < NN) H[(size_t)row * DD + col] = f2bf(acc[mi][ni][j]);
            }
        }
    }
}

// ---------------- FUSED spmm1 + gemm2: H2 = relu(A·H1·nd+b1)·ns @ W2t^T ----
// Block = 256 threads (4 waves) handles 64 nodes. Phase 1: wave w gathers
// nodes w*16..w*16+15 (same code as k_spmm_bf), applies relu(·nd+b1)·ns,
// packs bf16 rows into a 64x256 LDS tile (32 KB, XOR-swizzled 16B chunks).
// Phase 2: 64x256 @ 256x256 MFMA, wave w owns cols w*64..w*64+63, B frags
// straight from L2-resident W2t. Eliminates the standalone gemm2 dispatch
// plus the 51 MB x1n store + 51 MB reload. Bit-identical numerics to the
// unfused pipeline (same bf16 values, same MFMA k-order).
__global__ __launch_bounds__(256, 4) void k_spgemm(const ushort* __restrict__ H1,
                                                   const int* __restrict__ rowptr,
                                                   const int* __restrict__ eidx,
                                                   const float* __restrict__ nd,
                                                   const float* __restrict__ ns,
                                                   const float* __restrict__ b1,
                                                   const ushort* __restrict__ Wt2,
                                                   ushort* __restrict__ H2) {
    __shared__ uint4 xs[64 * 32];  // 64 rows x 32 chunks of 16B, swizzled
    int t = threadIdx.x;
    int lane = t & 63, w = t >> 6;
    int nodebase = blockIdx.x * 64;
    int c = lane << 2;  // bf16 col
    float4 bb = *(const float4*)(b1 + c);

    // ---- phase 1: gather + epilogue-1 + LDS pack ----
#pragma unroll 1
    for (int jj = 0; jj < 16; ++jj) {
        int jrow = w * 16 + jj;
        int node = nodebase + jrow;
        if (node < NN) {
            uint2 sv = *(const uint2*)(H1 + (size_t)node * DD + c);  // self-loop
            float p0[4], p1[4], p2[4], p3[4];
            p0[0] = __uint_as_float(sv.x << 16);
            p0[1] = __uint_as_float(sv.x & 0xffff0000u);
            p0[2] = __uint_as_float(sv.y << 16);
            p0[3] = __uint_as_float(sv.y & 0xffff0000u);
#pragma unroll
            for (int j = 0; j < 4; ++j) { p1[j] = 0.f; p2[j] = 0.f; p3[j] = 0.f; }
            int e = rowptr[node], end = rowptr[node + 1];
            for (; e + 3 < end; e += 4) {
                int s0 = eidx[e], s1 = eidx[e + 1], s2 = eidx[e + 2], s3 = eidx[e + 3];
                uint2 v0 = *(const uint2*)(H1 + (size_t)s0 * DD + c);
                uint2 v1 = *(const uint2*)(H1 + (size_t)s1 * DD + c);
                uint2 v2 = *(const uint2*)(H1 + (size_t)s2 * DD + c);
                uint2 v3 = *(const uint2*)(H1 + (size_t)s3 * DD + c);
                p0[0] += __uint_as_float(v0.x << 16);
                p0[1] += __uint_as_float(v0.x & 0xffff0000u);
                p0[2] += __uint_as_float(v0.y << 16);
                p0[3] += __uint_as_float(v0.y & 0xffff0000u);
                p1[0] += __uint_as_float(v1.x << 16);
                p1[1] += __uint_as_float(v1.x & 0xffff0000u);
                p1[2] += __uint_as_float(v1.y << 16);
                p1[3] += __uint_as_float(v1.y & 0xffff0000u);
                p2[0] += __uint_as_float(v2.x << 16);
                p2[1] += __uint_as_float(v2.x & 0xffff0000u);
                p2[2] += __uint_as_float(v2.y << 16);
                p2[3] += __uint_as_float(v2.y & 0xffff0000u);
                p3[0] += __uint_as_float(v3.x << 16);
                p3[1] += __uint_as_float(v3.x & 0xffff0000u);
                p3[2] += __uint_as_float(v3.y << 16);
                p3[3] += __uint_as_float(v3.y & 0xffff0000u);
            }
            for (; e < end; ++e) {
                int s0 = eidx[e];
                uint2 v0 = *(const uint2*)(H1 + (size_t)s0 * DD + c);
                p0[0] += __uint_as_float(v0.x << 16);
                p0[1] += __uint_as_float(v0.x & 0xffff0000u);
                p0[2] += __uint_as_float(v0.y << 16);
                p0[3] += __uint_as_float(v0.y & 0xffff0000u);
            }
#pragma unroll
            for (int j = 0; j < 4; ++j) p0[j] += (p1[j] + p2[j]) + p3[j];
            float n = nd[node];
            float s = ns[node];
            float o0 = fmaxf(fmaf(p0[0], n, bb.x), 0.f) * s;
            float o1 = fmaxf(fmaf(p0[1], n, bb.y), 0.f) * s;
            float o2 = fmaxf(fmaf(p0[2], n, bb.z), 0.f) * s;
            float o3 = fmaxf(fmaf(p0[3], n, bb.w), 0.f) * s;
            uint lo = (uint)f2bf(o0) | ((uint)f2bf(o1) << 16);
            uint hi = (uint)f2bf(o2) | ((uint)f2bf(o3) << 16);
            int ch = lane >> 1, h = lane & 1;
            ((uint2*)&xs[jrow * 32 + (ch ^ (jrow & 7))])[h] = make_uint2(lo, hi);
        }
    }
    __syncthreads();

    // ---- phase 2: 64x256 @ W2t^T ----
    int lg = lane >> 4, lr = lane & 15;
    const uint4* wb[4];
#pragma unroll
    for (int ni = 0; ni < 4; ++ni)
        wb[ni] = (const uint4*)(Wt2 + (size_t)(w * 64 + ni * 16 + lr) * DD);

    fx4 acc[4][4];
#pragma unroll
    for (int mi = 0; mi < 4; ++mi)
#pragma unroll
        for (int ni = 0; ni < 4; ++ni)
            acc[mi][ni] = (fx4){0.f, 0.f, 0.f, 0.f};

#pragma unroll
    for (int kc = 0; kc < 8; ++kc) {
        bfx8 bfr[4], af[4];
#pragma unroll
        for (int ni = 0; ni < 4; ++ni)
            bfr[ni] = *(const bfx8*)&wb[ni][kc * 4 + lg];
#pragma unroll
        for (int mi = 0; mi < 4; ++mi) {
            int r = mi * 16 + lr;
            af[mi] = *(const bfx8*)&xs[r * 32 + ((kc * 4 + lg) ^ (r & 7))];
        }
#pragma unroll
        for (int mi = 0; mi < 4; ++mi)
#pragma unroll
            for (int ni = 0; ni < 4; ++ni)
                acc[mi][ni] = __builtin_amdgcn_mfma_f32_16x16x32_bf16(
                    af[mi], bfr[ni], acc[mi][ni], 0, 0, 0);
    }

    // epilogue: C/D layout col=lane&15, row=(lane>>4)*4+reg
#pragma unroll
    for (int mi = 0; mi < 4; ++mi) {
        int rbase = nodebase + mi * 16 + lg * 4;
#pragma unroll
        for (int ni = 0; ni < 4; ++ni) {
            int col = w * 64 + ni * 16 + lr;
#pragma unroll
            for (int j = 0; j < 4; ++j) {
                int row = rbase + j;
                if (row < NN) H2[(size_t)row * DD + col] = f2bf(acc[mi][ni][j]);
            }
        }
    }
}

// ---------------- SpMM layer 2 (bf16 gather, fp32 accum + bias) ----------
__global__ __launch_bounds__(256) void k_spmm_bf(const ushort* __restrict__ T,
                                                 const int* __restrict__ rowptr,
                                                 const int* __restrict__ eidx,
                                                 const float* __restrict__ nd,
                                                 const float* __restrict__ bias,
                                                 float* __restrict__ of) {
    int wid = threadIdx.x >> 6, lane = threadIdx.x & 63;
    int node = blockIdx.x * 4 + wid;
    if (node >= NN) return;
    int c = lane << 2;  // 4 bf16 per lane
    uint2 sv = *(const uint2*)(T + (size_t)node * DD + c);  // self-loop
    float p0[4], p1[4], p2[4], p3[4];
    p0[0] = __uint_as_float(sv.x << 16);
    p0[1] = __uint_as_float(sv.x & 0xffff0000u);
    p0[2] = __uint_as_float(sv.y << 16);
    p0[3] = __uint_as_float(sv.y & 0xffff0000u);
#pragma unroll
    for (int j = 0; j < 4; ++j) { p1[j] = 0.f; p2[j] = 0.f; p3[j] = 0.f; }
    int e = rowptr[node], end = rowptr[node + 1];
    for (; e + 3 < end; e += 4) {
        int s0 = eidx[e], s1 = eidx[e + 1], s2 = eidx[e + 2], s3 = eidx[e + 3];
        uint2 v0 = *(const uint2*)(T + (size_t)s0 * DD + c);
        uint2 v1 = *(const uint2*)(T + (size_t)s1 * DD + c);
        uint2 v2 = *(const uint2*)(T + (size_t)s2 * DD + c);
        uint2 v3 = *(const uint2*)(T + (size_t)s3 * DD + c);
        p0[0] += __uint_as_float(v0.x << 16);
        p0[1] += __uint_as_float(v0.x & 0xffff0000u);
        p0[2] += __uint_as_float(v0.y << 16);
        p0[3] += __uint_as_float(v0.y & 0xffff0000u);
        p1[0] += __uint_as_float(v1.x << 16);
        p1[1] += __uint_as_float(v1.x & 0xffff0000u);
        p1[2] += __uint_as_float(v1.y << 16);
        p1[3] += __uint_as_float(v1.y & 0xffff0000u);
        p2[0] += __uint_as_float(v2.x << 16);
        p2[1] += __uint_as_float(v2.x & 0xffff0000u);
        p2[2] += __uint_as_float(v2.y << 16);
        p2[3] += __uint_as_float(v2.y & 0xffff0000u);
        p3[0] += __uint_as_float(v3.x << 16);
        p3[1] += __uint_as_float(v3.x & 0xffff0000u);
        p3[2] += __uint_as_float(v3.y << 16);
        p3[3] += __uint_as_float(v3.y & 0xffff0000u);
    }
    for (; e < end; ++e) {
        int s0 = eidx[e];
        uint2 v0 = *(const uint2*)(T + (size_t)s0 * DD + c);
        p0[0] += __uint_as_float(v0.x << 16);
        p0[1] += __uint_as_float(v0.x & 0xffff0000u);
        p0[2] += __uint_as_float(v0.y << 16);
        p0[3] += __uint_as_float(v0.y & 0xffff0000u);
    }
#pragma unroll
    for (int j = 0; j < 4; ++j) p0[j] += (p1[j] + p2[j]) + p3[j];
    float n = nd[node];
    float4 bb = *(const float4*)(bias + c);
    fx4 o = {fmaf(p0[0], n, bb.x), fmaf(p0[1], n, bb.y),
             fmaf(p0[2], n, bb.z), fmaf(p0[3], n, bb.w)};
    __builtin_nontemporal_store(o, (fx4*)(of + (size_t)node * DD + c));
}

extern "C" void kernel_launch(void* const* d_in, const int* in_sizes, int n_in,
                              void* d_out, int out_size, void* d_ws, size_t ws_size,
                              hipStream_t stream) {
    const float* features = (const float*)d_in[0];
    const int* src = (const int*)d_in[1];
    const int* dst = (const int*)d_in[2];
    const float* W1 = (const float*)d_in[3];
    const float* b1 = (const float*)d_in[4];
    const float* W2 = (const float*)d_in[5];
    const float* b2 = (const float*)d_in[6];
    int E = in_sizes[1];
    float* out = (float*)d_out;

    size_t off = 0;
    auto alloc = [&](size_t nbytes) -> void* {
        void* p = (char*)d_ws + off;
        off += (nbytes + 255) & ~(size_t)255;
        return p;
    };
    int* dego = (int*)alloc((size_t)NN * 4);
    int* degi = (int*)alloc((size_t)NN * 4);
    float* norm_src = (float*)alloc((size_t)NN * 4);
    float* norm_dst = (float*)alloc((size_t)NN * 4);
    int* rowptr = (int*)alloc((size_t)(NN + 1) * 4);
    int* cursor = (int*)alloc((size_t)NN * 4);
    int* partials = (int*)alloc(128 * 4);
    int* eidx = (int*)alloc((size_t)E * 4);
    ushort* Wt1 = (ushort*)alloc((size_t)DD * DD * 2);
    ushort* Wt2 = (ushort*)alloc((size_t)DD * DD * 2);
    ushort* Hbf = (ushort*)alloc((size_t)NN * DD * 2);   // H1
    ushort* H2bf = (ushort*)alloc((size_t)NN * DD * 2);  // H2

    const int NB = (NN + SCAN_BLK - 1) / SCAN_BLK;  // 98

    k_init_deg<<<(NN + 255) / 256, 256, 0, stream>>>(dego, degi);
    k_count<<<(E + 255) / 256, 256, 0, stream>>>(src, dst, E, dego, degi);
    k_norm<<<(NN + 255) / 256, 256, 0, stream>>>(dego, degi, norm_src, norm_dst);
    k_scan1<<<NB, SCAN_BLK, 0, stream>>>(degi, partials);
    k_scan2<<<1, 128, 0, stream>>>(partials, NB);
    k_scan3<<<NB, SCAN_BLK, 0, stream>>>(degi, partials, rowptr, cursor);
    k_fill<<<(E + 255) / 256, 256, 0, stream>>>(src, dst, E, cursor, eidx);

    k_convW<<<DD, DD, 0, stream>>>(W1, Wt1);
    k_convW<<<DD, DD, 0, stream>>>(W2, Wt2);

    // layer 1 GEMM: H1 = (X*ns) @ W1
    dim3 ggrid((NN + 127) / 128);  // 782
    k_mfgemm<true><<<ggrid, 512, 0, stream>>>(features, norm_src, Wt1, Hbf);
    // fused spmm1 + gemm2: H2 = relu(A·H1·nd + b1)·ns @ W2
    k_spgemm<<<(NN + 63) / 64, 256, 0, stream>>>(Hbf, rowptr, eidx, norm_dst,
                                                 norm_src, b1, Wt2, H2bf);
    // spmm2: out = A·H2·nd + b2
    k_spmm_bf<<<(NN + 3) / 4, 256, 0, stream>>>(H2bf, rowptr, eidx, norm_dst,
                                                b2, out);
}

// Round 9
// 398.670 us; speedup vs baseline: 1.0021x; 1.0021x over previous
//
#include <hip/hip_runtime.h>

#define NN 100000
#define DD 256
#define SCAN_BLK 1024

typedef unsigned int uint;
typedef unsigned short ushort;
typedef __attribute__((ext_vector_type(8))) short bfx8;
typedef __attribute__((ext_vector_type(4))) float fx4;

__device__ __forceinline__ ushort f2bf(float f) {  // RNE
    uint u = __float_as_uint(f);
    u += 0x7fff + ((u >> 16) & 1);
    return (ushort)(u >> 16);
}

__device__ __forceinline__ uint cvtpk(float lo, float hi) {  // 2xf32 -> packed bf16
    uint r;
    asm("v_cvt_pk_bf16_f32 %0, %1, %2" : "=v"(r) : "v"(lo), "v"(hi));
    return r;
}

// ---------------- degree / norm (deg arrays memset to 0 by host-side async) --
__global__ __launch_bounds__(256) void k_count(const int* __restrict__ src,
                                               const int* __restrict__ dst, int E,
                                               int* __restrict__ dego,
                                               int* __restrict__ degi) {
    int e = blockIdx.x * 256 + threadIdx.x;
    if (e < E) {
        atomicAdd(&dego[src[e]], 1);
        atomicAdd(&degi[dst[e]], 1);
    }
}

__global__ __launch_bounds__(256) void k_norm(const int* __restrict__ dego,
                                              const int* __restrict__ degi,
                                              float* __restrict__ ns,
                                              float* __restrict__ nd) {
    int i = blockIdx.x * 256 + threadIdx.x;
    if (i < NN) {
        ns[i] = rsqrtf((float)(dego[i] + 1));  // +1 = self-loop
        nd[i] = rsqrtf((float)(degi[i] + 1));
    }
}

// ---------------- CSR build (scan by dst; degi = real in-edges) -------------
__device__ __forceinline__ int block_scan_inc(int v, int* sm) {
    int t = threadIdx.x;
    sm[t] = v;
    __syncthreads();
    for (int o = 1; o < SCAN_BLK; o <<= 1) {
        int x = (t >= o) ? sm[t - o] : 0;
        __syncthreads();
        sm[t] += x;
        __syncthreads();
    }
    return sm[t];
}

__global__ __launch_bounds__(SCAN_BLK) void k_scan1(const int* __restrict__ degi,
                                                    int* __restrict__ partials) {
    __shared__ int sm[SCAN_BLK];
    int i = blockIdx.x * SCAN_BLK + threadIdx.x;
    int v = (i < NN) ? degi[i] : 0;
    block_scan_inc(v, sm);
    if (threadIdx.x == 0) partials[blockIdx.x] = sm[SCAN_BLK - 1];
}

__global__ __launch_bounds__(128) void k_scan2(int* __restrict__ partials, int nb) {
    __shared__ int sm[128];
    int t = threadIdx.x;
    int v = (t < nb) ? partials[t] : 0;
    sm[t] = v;
    __syncthreads();
    for (int o = 1; o < 128; o <<= 1) {
        int x = (t >= o) ? sm[t - o] : 0;
        __syncthreads();
        sm[t] += x;
        __syncthreads();
    }
    if (t < nb) partials[t] = sm[t] - v;  // exclusive
}

__global__ __launch_bounds__(SCAN_BLK) void k_scan3(const int* __restrict__ degi,
                                                    const int* __restrict__ partials,
                                                    int* __restrict__ rowptr,
                                                    int* __restrict__ cursor) {
    __shared__ int sm[SCAN_BLK];
    int i = blockIdx.x * SCAN_BLK + threadIdx.x;
    int v = (i < NN) ? degi[i] : 0;
    int incl = block_scan_inc(v, sm);
    int excl = partials[blockIdx.x] + incl - v;
    if (i <= NN) rowptr[i] = excl;   // rowptr[NN] = E
    if (i < NN) cursor[i] = excl;
}

__global__ __launch_bounds__(256) void k_fill(const int* __restrict__ src,
                                              const int* __restrict__ dst, int E,
                                              int* __restrict__ cursor,
                                              int* __restrict__ eidx) {
    int e = blockIdx.x * 256 + threadIdx.x;
    if (e < E) {
        int d = dst[e];
        int p = atomicAdd(&cursor[d], 1);
        eidx[p] = src[e];
    }
}

// Wt[n][k] = bf16(W[k][n]), both weights in one launch (grid 512)
__global__ __launch_bounds__(256) void k_convW(const float* __restrict__ W1,
                                               const float* __restrict__ W2,
                                               ushort* __restrict__ Wt1,
                                               ushort* __restrict__ Wt2) {
    int n = blockIdx.x & 255, k = threadIdx.x;
    const float* W = (blockIdx.x < 256) ? W1 : W2;
    ushort* Wt = (blockIdx.x < 256) ? Wt1 : Wt2;
    Wt[n * DD + k] = f2bf(W[(size_t)k * DD + n]);
}

// ---------------- MFMA GEMM: H = A @ Wt^T (optionally row-scaled) ----------
// Tile 128x256 (A read once), BK=64, 512 threads (8 waves 2x4), wave tile
// 64x64. A staged via global_load_lds (16B) with PRE-SWIZZLED SOURCE (linear
// LDS dest, XOR-swizzled read — m173 pattern), double-buffered. All 8 B-frags
// of a K-step preloaded into regs ONCE (kills the per-kk L2-latency serial
// chain that left round-7's GEMM 97% idle). FP32A: A is raw fp32; convert at
// LDS-read via v_cvt_pk_bf16_f32 and apply row scale nrm in the EPILOGUE
// ((ns.X)@W == ns.(X@W)).
template <bool FP32A>
__global__ __launch_bounds__(512, 4) void k_mfgemm(const void* __restrict__ Av,
                                                   const float* __restrict__ nrm,
                                                   const ushort* __restrict__ Wt,
                                                   ushort* __restrict__ H) {
    constexpr int CPR = FP32A ? 16 : 8;           // 16B chunks per row per K-step
    constexpr int CALLS = (128 * CPR) / (8 * 64); // gload_lds calls per thread
    __shared__ uint4 atq[2][128 * CPR];
    int t = threadIdx.x;
    int brow = blockIdx.x * 128;
    int lane = t & 63, w = t >> 6;
    int wr = w >> 2, wc = w & 3;       // wave grid 2x4
    int lg = lane >> 4, lr = lane & 15;

    // per-call pre-swizzled global source byte offset (at ks=0)
    uint gofs[CALLS];
#pragma unroll
    for (int i = 0; i < CALLS; ++i) {
        int slot = (w * CALLS + i) * 64;           // wave-uniform LDS chunk base
        int r = slot / CPR + lane / CPR;           // lane's dest row
        int cs = (lane % CPR) ^ (r & 7);           // inverse-swizzled src chunk
        int row = brow + r;
        if (row >= NN) row = NN - 1;               // tail clamp (stores masked)
        if (FP32A)
            gofs[i] = (uint)(((size_t)row * DD + cs * 4) * 4);
        else
            gofs[i] = (uint)(((size_t)row * DD + cs * 8) * 2);
    }

    auto stage = [&](int buf, int ks) {
#pragma unroll
        for (int i = 0; i < CALLS; ++i) {
            int slot = (w * CALLS + i) * 64;
            const char* g = (const char*)Av + gofs[i] + ks * (FP32A ? 256 : 128);
            __builtin_amdgcn_global_load_lds(
                (const __attribute__((address_space(1))) uint*)g,
                (__attribute__((address_space(3))) uint*)&atq[buf][slot], 16, 0, 0);
        }
    };

    // B fragment pointers (L2-resident Wt)
    const uint4* wb[4];
#pragma unroll
    for (int ni = 0; ni < 4; ++ni)
        wb[ni] = (const uint4*)(Wt + (size_t)(wc * 64 + ni * 16 + lr) * DD);

    bfx8 bfr2[2][4];  // all 8 B-frags of current K-step
    auto ldB = [&](int ks) {
#pragma unroll
        for (int kk = 0; kk < 2; ++kk)
#pragma unroll
            for (int ni = 0; ni < 4; ++ni)
                bfr2[kk][ni] = *(const bfx8*)&wb[ni][ks * 8 + kk * 4 + lg];
    };

    fx4 acc[4][4];
#pragma unroll
    for (int mi = 0; mi < 4; ++mi)
#pragma unroll
        for (int ni = 0; ni < 4; ++ni)
            acc[mi][ni] = (fx4){0.f, 0.f, 0.f, 0.f};

    stage(0, 0);
    ldB(0);
    __syncthreads();

    int buf = 0;
#pragma unroll
    for (int ks = 0; ks < 4; ++ks) {
        if (ks < 3) stage(buf ^ 1, ks + 1);  // async into other buffer
#pragma unroll
        for (int kk = 0; kk < 2; ++kk) {
#pragma unroll
            for (int mi = 0; mi < 4; ++mi) {
                int r = wr * 64 + mi * 16 + lr;
                bfx8 af;
                if (FP32A) {
                    int cf = (kk * 4 + lg) * 2;
                    fx4 q0 = *(const fx4*)&atq[buf][r * 16 + (cf ^ (r & 7))];
                    fx4 q1 = *(const fx4*)&atq[buf][r * 16 + ((cf + 1) ^ (r & 7))];
                    uint4 uu;
                    uu.x = cvtpk(q0.x, q0.y);
                    uu.y = cvtpk(q0.z, q0.w);
                    uu.z = cvtpk(q1.x, q1.y);
                    uu.w = cvtpk(q1.z, q1.w);
                    af = *(bfx8*)&uu;
                } else {
                    int c = kk * 4 + lg;
                    af = *(const bfx8*)&atq[buf][r * 8 + (c ^ (r & 7))];
                }
#pragma unroll
                for (int ni = 0; ni < 4; ++ni)
                    acc[mi][ni] = __builtin_amdgcn_mfma_f32_16x16x32_bf16(
                        af, bfr2[kk][ni], acc[mi][ni], 0, 0, 0);
            }
        }
        if (ks < 3) ldB(ks + 1);  // issue after last consumer of bfr2
        __syncthreads();
        buf ^= 1;
    }

    // epilogue: C/D layout col=lane&15, row=(lane>>4)*4+reg (verified m89/m91)
#pragma unroll
    for (int mi = 0; mi < 4; ++mi) {
#pragma unroll
        for (int j = 0; j < 4; ++j) {
            int row = brow + wr * 64 + mi * 16 + lg * 4 + j;
            if (row < NN) {
                float sc = FP32A ? nrm[row] : 1.0f;
                ushort* hp = H + (size_t)row * DD;
#pragma unroll
                for (int ni = 0; ni < 4; ++ni) {
                    int col = wc * 64 + ni * 16 + lr;
                    hp[col] = f2bf(acc[mi][ni][j] * sc);
                }
            }
        }
    }
}

// ---------------- SpMM (bf16 gather, fp32 accum): one wave per dst node ----
// layer1: obf = bf16(relu(agg*nd + b) * ns)   (pre-scaled next-GEMM input)
// layer2: of  = agg*nd + b (final fp32, nontemporal store)
__global__ __launch_bounds__(256) void k_spmm_bf(const ushort* __restrict__ T,
                                                 const int* __restrict__ rowptr,
                                                 const int* __restrict__ eidx,
                                                 const float* __restrict__ nd,
                                                 const float* __restrict__ ns,
                                                 const float* __restrict__ bias,
                                                 ushort* __restrict__ obf,
                                                 float* __restrict__ of,
                                                 int layer1) {
    int wid = threadIdx.x >> 6, lane = threadIdx.x & 63;
    int node = blockIdx.x * 4 + wid;
    if (node >= NN) return;
    int c = lane << 2;  // 4 bf16 per lane
    uint2 sv = *(const uint2*)(T + (size_t)node * DD + c);  // self-loop
    float p0[4], p1[4], p2[4], p3[4];
    p0[0] = __uint_as_float(sv.x << 16);
    p0[1] = __uint_as_float(sv.x & 0xffff0000u);
    p0[2] = __uint_as_float(sv.y << 16);
    p0[3] = __uint_as_float(sv.y & 0xffff0000u);
#pragma unroll
    for (int j = 0; j < 4; ++j) { p1[j] = 0.f; p2[j] = 0.f; p3[j] = 0.f; }
    int e = rowptr[node], end = rowptr[node + 1];
    for (; e + 3 < end; e += 4) {
        int s0 = eidx[e], s1 = eidx[e + 1], s2 = eidx[e + 2], s3 = eidx[e + 3];
        uint2 v0 = *(const uint2*)(T + (size_t)s0 * DD + c);
        uint2 v1 = *(const uint2*)(T + (size_t)s1 * DD + c);
        uint2 v2 = *(const uint2*)(T + (size_t)s2 * DD + c);
        uint2 v3 = *(const uint2*)(T + (size_t)s3 * DD + c);
        p0[0] += __uint_as_float(v0.x << 16);
        p0[1] += __uint_as_float(v0.x & 0xffff0000u);
        p0[2] += __uint_as_float(v0.y << 16);
        p0[3] += __uint_as_float(v0.y & 0xffff0000u);
        p1[0] += __uint_as_float(v1.x << 16);
        p1[1] += __uint_as_float(v1.x & 0xffff0000u);
        p1[2] += __uint_as_float(v1.y << 16);
        p1[3] += __uint_as_float(v1.y & 0xffff0000u);
        p2[0] += __uint_as_float(v2.x << 16);
        p2[1] += __uint_as_float(v2.x & 0xffff0000u);
        p2[2] += __uint_as_float(v2.y << 16);
        p2[3] += __uint_as_float(v2.y & 0xffff0000u);
        p3[0] += __uint_as_float(v3.x << 16);
        p3[1] += __uint_as_float(v3.x & 0xffff0000u);
        p3[2] += __uint_as_float(v3.y << 16);
        p3[3] += __uint_as_float(v3.y & 0xffff0000u);
    }
    for (; e < end; ++e) {
        int s0 = eidx[e];
        uint2 v0 = *(const uint2*)(T + (size_t)s0 * DD + c);
        p0[0] += __uint_as_float(v0.x << 16);
        p0[1] += __uint_as_float(v0.x & 0xffff0000u);
        p0[2] += __uint_as_float(v0.y << 16);
        p0[3] += __uint_as_float(v0.y & 0xffff0000u);
    }
#pragma unroll
    for (int j = 0; j < 4; ++j) p0[j] += (p1[j] + p2[j]) + p3[j];
    float n = nd[node];
    float4 bb = *(const float4*)(bias + c);
    float o0 = fmaf(p0[0], n, bb.x);
    float o1 = fmaf(p0[1], n, bb.y);
    float o2 = fmaf(p0[2], n, bb.z);
    float o3 = fmaf(p0[3], n, bb.w);
    if (layer1) {
        float s = ns[node];
        o0 = fmaxf(o0, 0.f) * s; o1 = fmaxf(o1, 0.f) * s;
        o2 = fmaxf(o2, 0.f) * s; o3 = fmaxf(o3, 0.f) * s;
        uint lo = (uint)f2bf(o0) | ((uint)f2bf(o1) << 16);
        uint hi = (uint)f2bf(o2) | ((uint)f2bf(o3) << 16);
        *(uint2*)(obf + (size_t)node * DD + c) = make_uint2(lo, hi);
    } else {
        fx4 o = {o0, o1, o2, o3};
        __builtin_nontemporal_store(o, (fx4*)(of + (size_t)node * DD + c));
    }
}

extern "C" void kernel_launch(void* const* d_in, const int* in_sizes, int n_in,
                              void* d_out, int out_size, void* d_ws, size_t ws_size,
                              hipStream_t stream) {
    const float* features = (const float*)d_in[0];
    const int* src = (const int*)d_in[1];
    const int* dst = (const int*)d_in[2];
    const float* W1 = (const float*)d_in[3];
    const float* b1 = (const float*)d_in[4];
    const float* W2 = (const float*)d_in[5];
    const float* b2 = (const float*)d_in[6];
    int E = in_sizes[1];
    float* out = (float*)d_out;

    size_t off = 0;
    auto alloc = [&](size_t nbytes) -> void* {
        void* p = (char*)d_ws + off;
        off += (nbytes + 255) & ~(size_t)255;
        return p;
    };
    int* dego = (int*)alloc((size_t)NN * 4);      // offset 0
    int* degi = (int*)alloc((size_t)NN * 4);      // offset 400128 (contiguous)
    float* norm_src = (float*)alloc((size_t)NN * 4);
    float* norm_dst = (float*)alloc((size_t)NN * 4);
    int* rowptr = (int*)alloc((size_t)(NN + 1) * 4);
    int* cursor = (int*)alloc((size_t)NN * 4);
    int* partials = (int*)alloc(128 * 4);
    int* eidx = (int*)alloc((size_t)E * 4);
    ushort* Wt1 = (ushort*)alloc((size_t)DD * DD * 2);
    ushort* Wt2 = (ushort*)alloc((size_t)DD * DD * 2);
    ushort* Xbf = (ushort*)alloc((size_t)NN * DD * 2);
    ushort* Hbf = (ushort*)alloc((size_t)NN * DD * 2);

    const int NB = (NN + SCAN_BLK - 1) / SCAN_BLK;  // 98

    // zero both degree arrays in one async memset (they're adjacent in ws)
    hipMemsetAsync(dego, 0, (size_t)2 * 400128, stream);
    k_count<<<(E + 255) / 256, 256, 0, stream>>>(src, dst, E, dego, degi);
    k_norm<<<(NN + 255) / 256, 256, 0, stream>>>(dego, degi, norm_src, norm_dst);
    k_scan1<<<NB, SCAN_BLK, 0, stream>>>(degi, partials);
    k_scan2<<<1, 128, 0, stream>>>(partials, NB);
    k_scan3<<<NB, SCAN_BLK, 0, stream>>>(degi, partials, rowptr, cursor);
    k_fill<<<(E + 255) / 256, 256, 0, stream>>>(src, dst, E, cursor, eidx);
    k_convW<<<512, 256, 0, stream>>>(W1, W2, Wt1, Wt2);

    dim3 ggrid((NN + 127) / 128);  // 782, single column pass (BN=256)
    // layer 1: H1 = ns.(X @ W1)  (scale in epilogue)
    k_mfgemm<true><<<ggrid, 512, 0, stream>>>(features, norm_src, Wt1, Hbf);
    k_spmm_bf<<<(NN + 3) / 4, 256, 0, stream>>>(Hbf, rowptr, eidx, norm_dst,
                                                norm_src, b1, Xbf, out, 1);
    // layer 2
    k_mfgemm<false><<<ggrid, 512, 0, stream>>>(Xbf, nullptr, Wt2, Hbf);
    k_spmm_bf<<<(NN + 3) / 4, 256, 0, stream>>>(Hbf, rowptr, eidx, norm_dst,
                                                norm_src, b2, nullptr, out, 0);
}

// Round 11
// 398.283 us; speedup vs baseline: 1.0030x; 1.0010x over previous
//
#include <hip/hip_runtime.h>

#define NN 100000
#define DD 256
#define SCAN_BLK 1024

typedef unsigned int uint;
typedef unsigned short ushort;
typedef __attribute__((ext_vector_type(8))) short bfx8;
typedef __attribute__((ext_vector_type(4))) float fx4;

__device__ __forceinline__ ushort f2bf(float f) {  // RNE
    uint u = __float_as_uint(f);
    u += 0x7fff + ((u >> 16) & 1);
    return (ushort)(u >> 16);
}

__device__ __forceinline__ uint cvtpk(float lo, float hi) {  // 2xf32 -> packed bf16
    uint r;
    asm("v_cvt_pk_bf16_f32 %0, %1, %2" : "=v"(r) : "v"(lo), "v"(hi));
    return r;
}

// ---------------- degree / norm (deg arrays memset to 0 by host-side async) --
__global__ __launch_bounds__(256) void k_count(const int* __restrict__ src,
                                               const int* __restrict__ dst, int E,
                                               int* __restrict__ dego,
                                               int* __restrict__ degi) {
    int e = blockIdx.x * 256 + threadIdx.x;
    if (e < E) {
        atomicAdd(&dego[src[e]], 1);
        atomicAdd(&degi[dst[e]], 1);
    }
}

__global__ __launch_bounds__(256) void k_norm(const int* __restrict__ dego,
                                              const int* __restrict__ degi,
                                              float* __restrict__ ns,
                                              float* __restrict__ nd) {
    int i = blockIdx.x * 256 + threadIdx.x;
    if (i < NN) {
        ns[i] = rsqrtf((float)(dego[i] + 1));  // +1 = self-loop
        nd[i] = rsqrtf((float)(degi[i] + 1));
    }
}

// ---------------- CSR build (scan by dst; degi = real in-edges) -------------
__device__ __forceinline__ int block_scan_inc(int v, int* sm) {
    int t = threadIdx.x;
    sm[t] = v;
    __syncthreads();
    for (int o = 1; o < SCAN_BLK; o <<= 1) {
        int x = (t >= o) ? sm[t - o] : 0;
        __syncthreads();
        sm[t] += x;
        __syncthreads();
    }
    return sm[t];
}

__global__ __launch_bounds__(SCAN_BLK) void k_scan1(const int* __restrict__ degi,
                                                    int* __restrict__ partials) {
    __shared__ int sm[SCAN_BLK];
    int i = blockIdx.x * SCAN_BLK + threadIdx.x;
    int v = (i < NN) ? degi[i] : 0;
    block_scan_inc(v, sm);
    if (threadIdx.x == 0) partials[blockIdx.x] = sm[SCAN_BLK - 1];
}

__global__ __launch_bounds__(128) void k_scan2(int* __restrict__ partials, int nb) {
    __shared__ int sm[128];
    int t = threadIdx.x;
    int v = (t < nb) ? partials[t] : 0;
    sm[t] = v;
    __syncthreads();
    for (int o = 1; o < 128; o <<= 1) {
        int x = (t >= o) ? sm[t - o] : 0;
        __syncthreads();
        sm[t] += x;
        __syncthreads();
    }
    if (t < nb) partials[t] = sm[t] - v;  // exclusive
}

__global__ __launch_bounds__(SCAN_BLK) void k_scan3(const int* __restrict__ degi,
                                                    const int* __restrict__ partials,
                                                    int* __restrict__ rowptr,
                                                    int* __restrict__ cursor) {
    __shared__ int sm[SCAN_BLK];
    int i = blockIdx.x * SCAN_BLK + threadIdx.x;
    int v = (i < NN) ? degi[i] : 0;
    int incl = block_scan_inc(v, sm);
    int excl = partials[blockIdx.x] + incl - v;
    if (i <= NN) rowptr[i] = excl;   // rowptr[NN] = E
    if (i < NN) cursor[i] = excl;
}

__global__ __launch_bounds__(256) void k_fill(const int* __restrict__ src,
                                              const int* __restrict__ dst, int E,
                                              int* __restrict__ cursor,
                                              int* __restrict__ eidx) {
    int e = blockIdx.x * 256 + threadIdx.x;
    if (e < E) {
        int d = dst[e];
        int p = atomicAdd(&cursor[d], 1);
        eidx[p] = src[e];
    }
}

// Wt[n][k] = bf16(W[k][n]), both weights in one launch (grid 512)
__global__ __launch_bounds__(256) void k_convW(const float* __restrict__ W1,
                                               const float* __restrict__ W2,
                                               ushort* __restrict__ Wt1,
                                               ushort* __restrict__ Wt2) {
    int n = blockIdx.x & 255, k = threadIdx.x;
    const float* W = (blockIdx.x < 256) ? W1 : W2;
    ushort* Wt = (blockIdx.x < 256) ? Wt1 : Wt2;
    Wt[n * DD + k] = f2bf(W[(size_t)k * DD + n]);
}

// ---------------- MFMA GEMM: H = A @ Wt^T (optionally row-scaled) ----------
// Tile 128x256, BK=64, 512 threads (8 waves 2x4), wave tile 64x64. A staged
// via global_load_lds (pre-swizzled source, linear dest, swizzled read),
// double-buffered. All 8 B-frags per K-step preloaded once from L2-resident
// Wt. Staging structure byte-identical to round 9 (known-good).
// EPILOGUE: round-9 counters showed WRITE_SIZE 79.7 MB for a 51.2 MB output
// (1.56x amplification) from scattered per-ushort C-fragment stores. Fix:
// bounce through the first 32 KB of atq (reinterpreted as a 64x256 ushort
// tile) in TWO 64-row halves — waves with wr==h write their half (XOR-
// swizzled chunks), barrier, all threads read back and emit only full
// 128-B-line coalesced uint4 stores, barrier, next half.
template <bool FP32A>
__global__ __launch_bounds__(512, 4) void k_mfgemm(const void* __restrict__ Av,
                                                   const float* __restrict__ nrm,
                                                   const ushort* __restrict__ Wt,
                                                   ushort* __restrict__ H) {
    constexpr int CPR = FP32A ? 16 : 8;           // 16B chunks per row per K-step
    constexpr int CALLS = (128 * CPR) / (8 * 64); // gload_lds calls per thread
    __shared__ uint4 atq[2][128 * CPR];
    int t = threadIdx.x;
    int brow = blockIdx.x * 128;
    int lane = t & 63, w = t >> 6;
    int wr = w >> 2, wc = w & 3;       // wave grid 2x4
    int lg = lane >> 4, lr = lane & 15;

    // per-call pre-swizzled global source byte offset (at ks=0)
    uint gofs[CALLS];
#pragma unroll
    for (int i = 0; i < CALLS; ++i) {
        int slot = (w * CALLS + i) * 64;           // wave-uniform LDS chunk base
        int r = slot / CPR + lane / CPR;           // lane's dest row
        int cs = (lane % CPR) ^ (r & 7);           // inverse-swizzled src chunk
        int row = brow + r;
        if (row >= NN) row = NN - 1;               // tail clamp (stores masked)
        if (FP32A)
            gofs[i] = (uint)(((size_t)row * DD + cs * 4) * 4);
        else
            gofs[i] = (uint)(((size_t)row * DD + cs * 8) * 2);
    }

    auto stage = [&](int buf, int ks) {
#pragma unroll
        for (int i = 0; i < CALLS; ++i) {
            int slot = (w * CALLS + i) * 64;
            const char* g = (const char*)Av + gofs[i] + ks * (FP32A ? 256 : 128);
            __builtin_amdgcn_global_load_lds(
                (const __attribute__((address_space(1))) uint*)g,
                (__attribute__((address_space(3))) uint*)&atq[buf][slot], 16, 0, 0);
        }
    };

    // B fragment pointers (L2-resident Wt)
    const uint4* wb[4];
#pragma unroll
    for (int ni = 0; ni < 4; ++ni)
        wb[ni] = (const uint4*)(Wt + (size_t)(wc * 64 + ni * 16 + lr) * DD);

    bfx8 bfr2[2][4];  // all 8 B-frags of current K-step
    auto ldB = [&](int ks) {
#pragma unroll
        for (int kk = 0; kk < 2; ++kk)
#pragma unroll
            for (int ni = 0; ni < 4; ++ni)
                bfr2[kk][ni] = *(const bfx8*)&wb[ni][ks * 8 + kk * 4 + lg];
    };

    fx4 acc[4][4];
#pragma unroll
    for (int mi = 0; mi < 4; ++mi)
#pragma unroll
        for (int ni = 0; ni < 4; ++ni)
            acc[mi][ni] = (fx4){0.f, 0.f, 0.f, 0.f};

    stage(0, 0);
    ldB(0);
    __syncthreads();

    int buf = 0;
#pragma unroll
    for (int ks = 0; ks < 4; ++ks) {
        if (ks < 3) stage(buf ^ 1, ks + 1);  // async into other buffer
#pragma unroll
        for (int kk = 0; kk < 2; ++kk) {
#pragma unroll
            for (int mi = 0; mi < 4; ++mi) {
                int r = wr * 64 + mi * 16 + lr;
                bfx8 af;
                if (FP32A) {
                    int cf = (kk * 4 + lg) * 2;
                    fx4 q0 = *(const fx4*)&atq[buf][r * 16 + (cf ^ (r & 7))];
                    fx4 q1 = *(const fx4*)&atq[buf][r * 16 + ((cf + 1) ^ (r & 7))];
                    uint4 uu;
                    uu.x = cvtpk(q0.x, q0.y);
                    uu.y = cvtpk(q0.z, q0.w);
                    uu.z = cvtpk(q1.x, q1.y);
                    uu.w = cvtpk(q1.z, q1.w);
                    af = *(bfx8*)&uu;
                } else {
                    int c = kk * 4 + lg;
                    af = *(const bfx8*)&atq[buf][r * 8 + (c ^ (r & 7))];
                }
#pragma unroll
                for (int ni = 0; ni < 4; ++ni)
                    acc[mi][ni] = __builtin_amdgcn_mfma_f32_16x16x32_bf16(
                        af, bfr2[kk][ni], acc[mi][ni], 0, 0, 0);
            }
        }
        if (ks < 3) ldB(ks + 1);  // issue after last consumer of bfr2
        __syncthreads();
        buf ^= 1;
    }
    // K-loop ends with a barrier: all staging reads are complete.

    // ---- epilogue via LDS, two 64-row halves in the 32 KB scratch ----
    float scl[4][4];
    if (FP32A) {
#pragma unroll
        for (int mi = 0; mi < 4; ++mi)
#pragma unroll
            for (int j = 0; j < 4; ++j) {
                int row = brow + wr * 64 + mi * 16 + lg * 4 + j;
                scl[mi][j] = nrm[row < NN ? row : NN - 1];
            }
    }
    ushort* hs = (ushort*)&atq[0][0];  // 64 rows x 256 ushorts = 32768 B
#pragma unroll
    for (int h = 0; h < 2; ++h) {
        if (wr == h) {  // waves owning rows h*64..h*64+63 write their fragments
#pragma unroll
            for (int mi = 0; mi < 4; ++mi)
#pragma unroll
                for (int ni = 0; ni < 4; ++ni)
#pragma unroll
                    for (int j = 0; j < 4; ++j) {
                        int rl = mi * 16 + lg * 4 + j;   // 0..63 within half
                        int c = wc * 64 + ni * 16 + lr;
                        float v = acc[mi][ni][j];
                        if (FP32A) v *= scl[mi][j];
                        hs[rl * 256 + (((c >> 3) ^ (rl & 7)) << 3) + (c & 7)] =
                            f2bf(v);
                    }
        }
        __syncthreads();
        {   // coalesced readback: 8 threads/row, 4 x 16B each, 128B runs
            int rl = t >> 3;               // 0..63
            int grow = brow + h * 64 + rl;
            if (grow < NN) {
                ushort* hp = H + (size_t)grow * DD;
#pragma unroll
                for (int i = 0; i < 4; ++i) {
                    int ch = (t & 7) + i * 8;
                    uint4 v = *(const uint4*)&hs[rl * 256 + ((ch ^ (rl & 7)) << 3)];
                    *(uint4*)(hp + ch * 8) = v;
                }
            }
        }
        __syncthreads();
    }
}

// ---------------- SpMM (bf16 gather, fp32 accum): one wave per dst node ----
// layer1: obf = bf16(relu(agg*nd + b) * ns)   (pre-scaled next-GEMM input)
// layer2: of  = agg*nd + b (final fp32, nontemporal store)
__global__ __launch_bounds__(256) void k_spmm_bf(const ushort* __restrict__ T,
                                                 const int* __restrict__ rowptr,
                                                 const int* __restrict__ eidx,
                                                 const float* __restrict__ nd,
                                                 const float* __restrict__ ns,
                                                 const float* __restrict__ bias,
                                                 ushort* __restrict__ obf,
                                                 float* __restrict__ of,
                                                 int layer1) {
    int wid = threadIdx.x >> 6, lane = threadIdx.x & 63;
    int node = blockIdx.x * 4 + wid;
    if (node >= NN) return;
    int c = lane << 2;  // 4 bf16 per lane
    uint2 sv = *(const uint2*)(T + (size_t)node * DD + c);  // self-loop
    float p0[4], p1[4], p2[4], p3[4];
    p0[0] = __uint_as_float(sv.x << 16);
    p0[1] = __uint_as_float(sv.x & 0xffff0000u);
    p0[2] = __uint_as_float(sv.y << 16);
    p0[3] = __uint_as_float(sv.y & 0xffff0000u);
#pragma unroll
    for (int j = 0; j < 4; ++j) { p1[j] = 0.f; p2[j] = 0.f; p3[j] = 0.f; }
    int e = rowptr[node], end = rowptr[node + 1];
    for (; e + 3 < end; e += 4) {
        int s0 = eidx[e], s1 = eidx[e + 1], s2 = eidx[e + 2], s3 = eidx[e + 3];
        uint2 v0 = *(const uint2*)(T + (size_t)s0 * DD + c);
        uint2 v1 = *(const uint2*)(T + (size_t)s1 * DD + c);
        uint2 v2 = *(const uint2*)(T + (size_t)s2 * DD + c);
        uint2 v3 = *(const uint2*)(T + (size_t)s3 * DD + c);
        p0[0] += __uint_as_float(v0.x << 16);
        p0[1] += __uint_as_float(v0.x & 0xffff0000u);
        p0[2] += __uint_as_float(v0.y << 16);
        p0[3] += __uint_as_float(v0.y & 0xffff0000u);
        p1[0] += __uint_as_float(v1.x << 16);
        p1[1] += __uint_as_float(v1.x & 0xffff0000u);
        p1[2] += __uint_as_float(v1.y << 16);
        p1[3] += __uint_as_float(v1.y & 0xffff0000u);
        p2[0] += __uint_as_float(v2.x << 16);
        p2[1] += __uint_as_float(v2.x & 0xffff0000u);
        p2[2] += __uint_as_float(v2.y << 16);
        p2[3] += __uint_as_float(v2.y & 0xffff0000u);
        p3[0] += __uint_as_float(v3.x << 16);
        p3[1] += __uint_as_float(v3.x & 0xffff0000u);
        p3[2] += __uint_as_float(v3.y << 16);
        p3[3] += __uint_as_float(v3.y & 0xffff0000u);
    }
    for (; e < end; ++e) {
        int s0 = eidx[e];
        uint2 v0 = *(const uint2*)(T + (size_t)s0 * DD + c);
        p0[0] += __uint_as_float(v0.x << 16);
        p0[1] += __uint_as_float(v0.x & 0xffff0000u);
        p0[2] += __uint_as_float(v0.y << 16);
        p0[3] += __uint_as_float(v0.y & 0xffff0000u);
    }
#pragma unroll
    for (int j = 0; j < 4; ++j) p0[j] += (p1[j] + p2[j]) + p3[j];
    float n = nd[node];
    float4 bb = *(const float4*)(bias + c);
    float o0 = fmaf(p0[0], n, bb.x);
    float o1 = fmaf(p0[1], n, bb.y);
    float o2 = fmaf(p0[2], n, bb.z);
    float o3 = fmaf(p0[3], n, bb.w);
    if (layer1) {
        float s = ns[node];
        o0 = fmaxf(o0, 0.f) * s; o1 = fmaxf(o1, 0.f) * s;
        o2 = fmaxf(o2, 0.f) * s; o3 = fmaxf(o3, 0.f) * s;
        uint lo = (uint)f2bf(o0) | ((uint)f2bf(o1) << 16);
        uint hi = (uint)f2bf(o2) | ((uint)f2bf(o3) << 16);
        *(uint2*)(obf + (size_t)node * DD + c) = make_uint2(lo, hi);
    } else {
        fx4 o = {o0, o1, o2, o3};
        __builtin_nontemporal_store(o, (fx4*)(of + (size_t)node * DD + c));
    }
}

extern "C" void kernel_launch(void* const* d_in, const int* in_sizes, int n_in,
                              void* d_out, int out_size, void* d_ws, size_t ws_size,
                              hipStream_t stream) {
    const float* features = (const float*)d_in[0];
    const int* src = (const int*)d_in[1];
    const int* dst = (const int*)d_in[2];
    const float* W1 = (const float*)d_in[3];
    const float* b1 = (const float*)d_in[4];
    const float* W2 = (const float*)d_in[5];
    const float* b2 = (const float*)d_in[6];
    int E = in_sizes[1];
    float* out = (float*)d_out;

    size_t off = 0;
    auto alloc = [&](size_t nbytes) -> void* {
        void* p = (char*)d_ws + off;
        off += (nbytes + 255) & ~(size_t)255;
        return p;
    };
    int* dego = (int*)alloc((size_t)NN * 4);      // offset 0
    int* degi = (int*)alloc((size_t)NN * 4);      // offset 400128 (contiguous)
    float* norm_src = (float*)alloc((size_t)NN * 4);
    float* norm_dst = (float*)alloc((size_t)NN * 4);
    int* rowptr = (int*)alloc((size_t)(NN + 1) * 4);
    int* cursor = (int*)alloc((size_t)NN * 4);
    int* partials = (int*)alloc(128 * 4);
    int* eidx = (int*)alloc((size_t)E * 4);
    ushort* Wt1 = (ushort*)alloc((size_t)DD * DD * 2);
    ushort* Wt2 = (ushort*)alloc((size_t)DD * DD * 2);
    ushort* Xbf = (ushort*)alloc((size_t)NN * DD * 2);
    ushort* Hbf = (ushort*)alloc((size_t)NN * DD * 2);

    const int NB = (NN + SCAN_BLK - 1) / SCAN_BLK;  // 98

    // zero both degree arrays in one async memset (they're adjacent in ws)
    hipMemsetAsync(dego, 0, (size_t)2 * 400128, stream);
    k_count<<<(E + 255) / 256, 256, 0, stream>>>(src, dst, E, dego, degi);
    k_norm<<<(NN + 255) / 256, 256, 0, stream>>>(dego, degi, norm_src, norm_dst);
    k_scan1<<<NB, SCAN_BLK, 0, stream>>>(degi, partials);
    k_scan2<<<1, 128, 0, stream>>>(partials, NB);
    k_scan3<<<NB, SCAN_BLK, 0, stream>>>(degi, partials, rowptr, cursor);
    k_fill<<<(E + 255) / 256, 256, 0, stream>>>(src, dst, E, cursor, eidx);
    k_convW<<<512, 256, 0, stream>>>(W1, W2, Wt1, Wt2);

    dim3 ggrid((NN + 127) / 128);  // 782, single column pass (BN=256)
    // layer 1: H1 = ns.(X @ W1)  (scale in epilogue)
    k_mfgemm<true><<<ggrid, 512, 0, stream>>>(features, norm_src, Wt1, Hbf);
    k_spmm_bf<<<(NN + 3) / 4, 256, 0, stream>>>(Hbf, rowptr, eidx, norm_dst,
                                                norm_src, b1, Xbf, out, 1);
    // layer 2
    k_mfgemm<false><<<ggrid, 512, 0, stream>>>(Xbf, nullptr, Wt2, Hbf);
    k_spmm_bf<<<(NN + 3) / 4, 256, 0, stream>>>(Hbf, rowptr, eidx, norm_dst,
                                                norm_src, b2, nullptr, out, 0);
}

// Round 12
// 358.688 us; speedup vs baseline: 1.1138x; 1.1104x over previous
//
#include <hip/hip_runtime.h>

#define NN 100000
#define DD 256
#define SCAN_BLK 1024

typedef unsigned int uint;
typedef unsigned short ushort;
typedef __attribute__((ext_vector_type(8))) short bfx8;
typedef __attribute__((ext_vector_type(4))) float fx4;

__device__ __forceinline__ ushort f2bf(float f) {  // RNE
    uint u = __float_as_uint(f);
    u += 0x7fff + ((u >> 16) & 1);
    return (ushort)(u >> 16);
}

__device__ __forceinline__ uint cvtpk(float lo, float hi) {  // 2xf32 -> packed bf16
    uint r;
    asm("v_cvt_pk_bf16_f32 %0, %1, %2" : "=v"(r) : "v"(lo), "v"(hi));
    return r;
}

// ---------------- degree count (deg arrays memset to 0 host-side) ----------
__global__ __launch_bounds__(256) void k_count(const int* __restrict__ src,
                                               const int* __restrict__ dst, int E,
                                               int* __restrict__ dego,
                                               int* __restrict__ degi) {
    int e = blockIdx.x * 256 + threadIdx.x;
    if (e < E) {
        atomicAdd(&dego[src[e]], 1);
        atomicAdd(&degi[dst[e]], 1);
    }
}

// ---------------- CSR build (scan by dst; degi = real in-edges) -------------
__device__ __forceinline__ int block_scan_inc(int v, int* sm) {
    int t = threadIdx.x;
    sm[t] = v;
    __syncthreads();
    for (int o = 1; o < SCAN_BLK; o <<= 1) {
        int x = (t >= o) ? sm[t - o] : 0;
        __syncthreads();
        sm[t] += x;
        __syncthreads();
    }
    return sm[t];
}

// scan1 fused with norm computation (saves the k_norm launch)
__global__ __launch_bounds__(SCAN_BLK) void k_scan1n(const int* __restrict__ degi,
                                                     const int* __restrict__ dego,
                                                     int* __restrict__ partials,
                                                     float* __restrict__ ns,
                                                     float* __restrict__ nd) {
    __shared__ int sm[SCAN_BLK];
    int i = blockIdx.x * SCAN_BLK + threadIdx.x;
    int v = (i < NN) ? degi[i] : 0;
    if (i < NN) {
        ns[i] = rsqrtf((float)(dego[i] + 1));  // +1 = self-loop
        nd[i] = rsqrtf((float)(v + 1));
    }
    block_scan_inc(v, sm);
    if (threadIdx.x == 0) partials[blockIdx.x] = sm[SCAN_BLK - 1];
}

// scan2 fused with the W -> fragment-order Wf permutation (block 0 scans,
// blocks 1..64 convert). Wf layout: frag (c16,kf) holds cols c16*16..+15,
// k kf*32..+31; lane l owns col c16*16+(l&15), k kf*32+(l>>4)*8 .. +7, stored
// contiguously at Wf[((c16*8+kf)*64 + l)*8]. A wave's bfx8 B-load is then 64
// lanes x 16 B CONTIGUOUS (1 KB burst) instead of a 16-cache-line gather.
__global__ __launch_bounds__(256) void k_scan2cw(int* __restrict__ partials, int nb,
                                                 const float* __restrict__ W1,
                                                 const float* __restrict__ W2,
                                                 ushort* __restrict__ Wf1,
                                                 ushort* __restrict__ Wf2) {
    if (blockIdx.x == 0) {
        __shared__ int sm[128];
        int t = threadIdx.x;
        int v = (t < 128 && t < nb) ? partials[t] : 0;
        if (t < 128) sm[t] = v;
        __syncthreads();
        for (int o = 1; o < 128; o <<= 1) {
            int x = (t < 128 && t >= o) ? sm[t - o] : 0;
            __syncthreads();
            if (t < 128) sm[t] += x;
            __syncthreads();
        }
        if (t < nb) partials[t] = sm[t] - v;  // exclusive
    } else {
        int tid = (blockIdx.x - 1) * 256 + threadIdx.x;  // 0..16383
        int m = tid >> 13;
        int r = tid & 8191;                   // (c16,kf,lane) id
        int lane = r & 63;
        int kf = (r >> 6) & 7;
        int c16 = r >> 9;
        int n = c16 * 16 + (lane & 15);
        int kb = kf * 32 + (lane >> 4) * 8;
        const float* W = m ? W2 : W1;
        ushort* Wf = m ? Wf2 : Wf1;
        uint4 u;
        u.x = (uint)f2bf(W[(size_t)(kb + 0) * DD + n]) |
              ((uint)f2bf(W[(size_t)(kb + 1) * DD + n]) << 16);
        u.y = (uint)f2bf(W[(size_t)(kb + 2) * DD + n]) |
              ((uint)f2bf(W[(size_t)(kb + 3) * DD + n]) << 16);
        u.z = (uint)f2bf(W[(size_t)(kb + 4) * DD + n]) |
              ((uint)f2bf(W[(size_t)(kb + 5) * DD + n]) << 16);
        u.w = (uint)f2bf(W[(size_t)(kb + 6) * DD + n]) |
              ((uint)f2bf(W[(size_t)(kb + 7) * DD + n]) << 16);
        *(uint4*)&Wf[(size_t)r * 8] = u;
    }
}

__global__ __launch_bounds__(SCAN_BLK) void k_scan3(const int* __restrict__ degi,
                                                    const int* __restrict__ partials,
                                                    int* __restrict__ rowptr,
                                                    int* __restrict__ cursor) {
    __shared__ int sm[SCAN_BLK];
    int i = blockIdx.x * SCAN_BLK + threadIdx.x;
    int v = (i < NN) ? degi[i] : 0;
    int incl = block_scan_inc(v, sm);
    int excl = partials[blockIdx.x] + incl - v;
    if (i <= NN) rowptr[i] = excl;   // rowptr[NN] = E
    if (i < NN) cursor[i] = excl;
}

__global__ __launch_bounds__(256) void k_fill(const int* __restrict__ src,
                                              const int* __restrict__ dst, int E,
                                              int* __restrict__ cursor,
                                              int* __restrict__ eidx) {
    int e = blockIdx.x * 256 + threadIdx.x;
    if (e < E) {
        int d = dst[e];
        int p = atomicAdd(&cursor[d], 1);
        eidx[p] = src[e];
    }
}

// ---------------- MFMA GEMM: H = A @ W (optionally row-scaled) -------------
// Tile 128x256, BK=64, 512 threads (8 waves 2x4), wave tile 64x64. 32 KB LDS
// for BOTH variants (round-7's best-measured A staging):
//   FP32A:  reg-staged — load f32, cvt_pk to bf16, ds_write swizzled (T14).
//   !FP32A: global_load_lds direct (pre-swizzled source, linear dest).
// B from the fragment-order Wf (L2-resident): per K-step all 8 frags
// preloaded as 1 KB coalesced bursts. Epilogue via LDS halves (coalesced).
template <bool FP32A>
__global__ __launch_bounds__(512, 4) void k_mfgemm(const void* __restrict__ Av,
                                                   const float* __restrict__ nrm,
                                                   const ushort* __restrict__ Wf,
                                                   ushort* __restrict__ H) {
    __shared__ uint4 atq[2][128 * 8];  // A tile bf16 [128r][8 chunks], dbuf, 32 KB
    int t = threadIdx.x;
    int brow = blockIdx.x * 128;
    int lane = t & 63, w = t >> 6;
    int wr = w >> 2, wc = w & 3;       // wave grid 2x4
    int lg = lane >> 4, lr = lane & 15;

    // ---- A staging setup ----
    int sr = t >> 3, sc = t & 7;       // reg-staging coords (FP32A)
    int rows_[2];
#pragma unroll
    for (int i = 0; i < 2; ++i) {
        int r = brow + sr + i * 64;
        rows_[i] = (r < NN) ? r : NN - 1;  // tail clamp (stores masked)
    }
    float4 svf[2][2];
    uint gofs[2];                      // gload_lds coords (!FP32A)
    if (!FP32A) {
#pragma unroll
        for (int i = 0; i < 2; ++i) {
            int slot = (w * 2 + i) * 64;
            int r = slot / 8 + lane / 8;
            int cs = (lane & 7) ^ (r & 7);
            int row = brow + r;
            if (row >= NN) row = NN - 1;
            gofs[i] = (uint)(((size_t)row * DD + cs * 8) * 2);
        }
    }

    auto ldA = [&](int ks) {  // FP32A: issue global loads early
        const float* X = (const float*)Av;
#pragma unroll
        for (int i = 0; i < 2; ++i) {
            const float4* p =
                (const float4*)(X + (size_t)rows_[i] * DD + ks * 64 + sc * 8);
            svf[i][0] = p[0];
            svf[i][1] = p[1];
        }
    };
    auto wrA = [&](int buf) {  // FP32A: convert + swizzled LDS write (late)
#pragma unroll
        for (int i = 0; i < 2; ++i) {
            int r = sr + i * 64;
            uint4 u;
            u.x = cvtpk(svf[i][0].x, svf[i][0].y);
            u.y = cvtpk(svf[i][0].z, svf[i][0].w);
            u.z = cvtpk(svf[i][1].x, svf[i][1].y);
            u.w = cvtpk(svf[i][1].z, svf[i][1].w);
            atq[buf][r * 8 + (sc ^ (r & 7))] = u;
        }
    };
    auto stage = [&](int buf, int ks) {  // !FP32A: async direct-to-LDS
#pragma unroll
        for (int i = 0; i < 2; ++i) {
            int slot = (w * 2 + i) * 64;
            const char* g = (const char*)Av + gofs[i] + ks * 128;
            __builtin_amdgcn_global_load_lds(
                (const __attribute__((address_space(1))) uint*)g,
                (__attribute__((address_space(3))) uint*)&atq[buf][slot], 16, 0, 0);
        }
    };

    // ---- B: fragment-order, coalesced 1 KB bursts ----
    bfx8 bfr2[2][4];
    auto ldB = [&](int ks) {
#pragma unroll
        for (int kk = 0; kk < 2; ++kk)
#pragma unroll
            for (int ni = 0; ni < 4; ++ni)
                bfr2[kk][ni] = *(const bfx8*)&Wf[
                    (((size_t)(wc * 4 + ni) * 8 + (ks * 2 + kk)) * 64 + lane) * 8];
    };

    fx4 acc[4][4];
#pragma unroll
    for (int mi = 0; mi < 4; ++mi)
#pragma unroll
        for (int ni = 0; ni < 4; ++ni)
            acc[mi][ni] = (fx4){0.f, 0.f, 0.f, 0.f};

    if (FP32A) { ldA(0); wrA(0); } else stage(0, 0);
    ldB(0);
    __syncthreads();

    int buf = 0;
#pragma unroll
    for (int ks = 0; ks < 4; ++ks) {
        if (ks < 3) {
            if (FP32A) ldA(ks + 1);      // issue early: hide under MFMA
            else stage(buf ^ 1, ks + 1); // async into other buffer
        }
#pragma unroll
        for (int kk = 0; kk < 2; ++kk) {
#pragma unroll
            for (int mi = 0; mi < 4; ++mi) {
                int r = wr * 64 + mi * 16 + lr;
                int c = kk * 4 + lg;
                bfx8 af = *(const bfx8*)&atq[buf][r * 8 + (c ^ (r & 7))];
#pragma unroll
                for (int ni = 0; ni < 4; ++ni)
                    acc[mi][ni] = __builtin_amdgcn_mfma_f32_16x16x32_bf16(
                        af, bfr2[kk][ni], acc[mi][ni], 0, 0, 0);
            }
        }
        if (ks < 3) {
            if (FP32A) wrA(buf ^ 1);     // write late, other buffer
            ldB(ks + 1);                 // after last consumer of bfr2
        }
        __syncthreads();
        buf ^= 1;
    }
    // K-loop ends with a barrier: staging reads complete, atq reusable.

    // ---- epilogue via LDS, two 64-row halves (coalesced 16B stores) ----
    float scl[4][4];
    if (FP32A) {
#pragma unroll
        for (int mi = 0; mi < 4; ++mi)
#pragma unroll
            for (int j = 0; j < 4; ++j) {
                int row = brow + wr * 64 + mi * 16 + lg * 4 + j;
                scl[mi][j] = nrm[row < NN ? row : NN - 1];
            }
    }
    ushort* hs = (ushort*)&atq[0][0];  // 64 rows x 256 ushorts = 32 KB
#pragma unroll
    for (int h = 0; h < 2; ++h) {
        if (wr == h) {
#pragma unroll
            for (int mi = 0; mi < 4; ++mi)
#pragma unroll
                for (int ni = 0; ni < 4; ++ni)
#pragma unroll
                    for (int j = 0; j < 4; ++j) {
                        int rl = mi * 16 + lg * 4 + j;   // 0..63 within half
                        int c = wc * 64 + ni * 16 + lr;
                        float v = acc[mi][ni][j];
                        if (FP32A) v *= scl[mi][j];
                        hs[rl * 256 + (((c >> 3) ^ (rl & 7)) << 3) + (c & 7)] =
                            f2bf(v);
                    }
        }
        __syncthreads();
        {
            int rl = t >> 3;               // 0..63
            int grow = brow + h * 64 + rl;
            if (grow < NN) {
                ushort* hp = H + (size_t)grow * DD;
#pragma unroll
                for (int i = 0; i < 4; ++i) {
                    int ch = (t & 7) + i * 8;
                    uint4 v = *(const uint4*)&hs[rl * 256 + ((ch ^ (rl & 7)) << 3)];
                    *(uint4*)(hp + ch * 8) = v;
                }
            }
        }
        __syncthreads();
    }
}

// ---------------- SpMM (bf16 gather, fp32 accum): one wave per dst node ----
__global__ __launch_bounds__(256) void k_spmm_bf(const ushort* __restrict__ T,
                                                 const int* __restrict__ rowptr,
                                                 const int* __restrict__ eidx,
                                                 const float* __restrict__ nd,
                                                 const float* __restrict__ ns,
                                                 const float* __restrict__ bias,
                                                 ushort* __restrict__ obf,
                                                 float* __restrict__ of,
                                                 int layer1) {
    int wid = threadIdx.x >> 6, lane = threadIdx.x & 63;
    int node = blockIdx.x * 4 + wid;
    if (node >= NN) return;
    int c = lane << 2;  // 4 bf16 per lane
    uint2 sv = *(const uint2*)(T + (size_t)node * DD + c);  // self-loop
    float p0[4], p1[4], p2[4], p3[4];
    p0[0] = __uint_as_float(sv.x << 16);
    p0[1] = __uint_as_float(sv.x & 0xffff0000u);
    p0[2] = __uint_as_float(sv.y << 16);
    p0[3] = __uint_as_float(sv.y & 0xffff0000u);
#pragma unroll
    for (int j = 0; j < 4; ++j) { p1[j] = 0.f; p2[j] = 0.f; p3[j] = 0.f; }
    int e = rowptr[node], end = rowptr[node + 1];
    for (; e + 3 < end; e += 4) {
        int s0 = eidx[e], s1 = eidx[e + 1], s2 = eidx[e + 2], s3 = eidx[e + 3];
        uint2 v0 = *(const uint2*)(T + (size_t)s0 * DD + c);
        uint2 v1 = *(const uint2*)(T + (size_t)s1 * DD + c);
        uint2 v2 = *(const uint2*)(T + (size_t)s2 * DD + c);
        uint2 v3 = *(const uint2*)(T + (size_t)s3 * DD + c);
        p0[0] += __uint_as_float(v0.x << 16);
        p0[1] += __uint_as_float(v0.x & 0xffff0000u);
        p0[2] += __uint_as_float(v0.y << 16);
        p0[3] += __uint_as_float(v0.y & 0xffff0000u);
        p1[0] += __uint_as_float(v1.x << 16);
        p1[1] += __uint_as_float(v1.x & 0xffff0000u);
        p1[2] += __uint_as_float(v1.y << 16);
        p1[3] += __uint_as_float(v1.y & 0xffff0000u);
        p2[0] += __uint_as_float(v2.x << 16);
        p2[1] += __uint_as_float(v2.x & 0xffff0000u);
        p2[2] += __uint_as_float(v2.y << 16);
        p2[3] += __uint_as_float(v2.y & 0xffff0000u);
        p3[0] += __uint_as_float(v3.x << 16);
        p3[1] += __uint_as_float(v3.x & 0xffff0000u);
        p3[2] += __uint_as_float(v3.y << 16);
        p3[3] += __uint_as_float(v3.y & 0xffff0000u);
    }
    for (; e < end; ++e) {
        int s0 = eidx[e];
        uint2 v0 = *(const uint2*)(T + (size_t)s0 * DD + c);
        p0[0] += __uint_as_float(v0.x << 16);
        p0[1] += __uint_as_float(v0.x & 0xffff0000u);
        p0[2] += __uint_as_float(v0.y << 16);
        p0[3] += __uint_as_float(v0.y & 0xffff0000u);
    }
#pragma unroll
    for (int j = 0; j < 4; ++j) p0[j] += (p1[j] + p2[j]) + p3[j];
    float n = nd[node];
    float4 bb = *(const float4*)(bias + c);
    float o0 = fmaf(p0[0], n, bb.x);
    float o1 = fmaf(p0[1], n, bb.y);
    float o2 = fmaf(p0[2], n, bb.z);
    float o3 = fmaf(p0[3], n, bb.w);
    if (layer1) {
        float s = ns[node];
        o0 = fmaxf(o0, 0.f) * s; o1 = fmaxf(o1, 0.f) * s;
        o2 = fmaxf(o2, 0.f) * s; o3 = fmaxf(o3, 0.f) * s;
        uint lo = (uint)f2bf(o0) | ((uint)f2bf(o1) << 16);
        uint hi = (uint)f2bf(o2) | ((uint)f2bf(o3) << 16);
        *(uint2*)(obf + (size_t)node * DD + c) = make_uint2(lo, hi);
    } else {
        fx4 o = {o0, o1, o2, o3};
        __builtin_nontemporal_store(o, (fx4*)(of + (size_t)node * DD + c));
    }
}

extern "C" void kernel_launch(void* const* d_in, const int* in_sizes, int n_in,
                              void* d_out, int out_size, void* d_ws, size_t ws_size,
                              hipStream_t stream) {
    const float* features = (const float*)d_in[0];
    const int* src = (const int*)d_in[1];
    const int* dst = (const int*)d_in[2];
    const float* W1 = (const float*)d_in[3];
    const float* b1 = (const float*)d_in[4];
    const float* W2 = (const float*)d_in[5];
    const float* b2 = (const float*)d_in[6];
    int E = in_sizes[1];
    float* out = (float*)d_out;

    size_t off = 0;
    auto alloc = [&](size_t nbytes) -> void* {
        void* p = (char*)d_ws + off;
        off += (nbytes + 255) & ~(size_t)255;
        return p;
    };
    int* dego = (int*)alloc((size_t)NN * 4);      // offset 0
    int* degi = (int*)alloc((size_t)NN * 4);      // offset 400128 (contiguous)
    float* norm_src = (float*)alloc((size_t)NN * 4);
    float* norm_dst = (float*)alloc((size_t)NN * 4);
    int* rowptr = (int*)alloc((size_t)(NN + 1) * 4);
    int* cursor = (int*)alloc((size_t)NN * 4);
    int* partials = (int*)alloc(128 * 4);
    int* eidx = (int*)alloc((size_t)E * 4);
    ushort* Wf1 = (ushort*)alloc((size_t)DD * DD * 2);
    ushort* Wf2 = (ushort*)alloc((size_t)DD * DD * 2);
    ushort* Xbf = (ushort*)alloc((size_t)NN * DD * 2);
    ushort* Hbf = (ushort*)alloc((size_t)NN * DD * 2);

    const int NB = (NN + SCAN_BLK - 1) / SCAN_BLK;  // 98

    hipMemsetAsync(dego, 0, (size_t)2 * 400128, stream);  // dego+degi adjacent
    k_count<<<(E + 255) / 256, 256, 0, stream>>>(src, dst, E, dego, degi);
    k_scan1n<<<NB, SCAN_BLK, 0, stream>>>(degi, dego, partials, norm_src, norm_dst);
    k_scan2cw<<<65, 256, 0, stream>>>(partials, NB, W1, W2, Wf1, Wf2);
    k_scan3<<<NB, SCAN_BLK, 0, stream>>>(degi, partials, rowptr, cursor);
    k_fill<<<(E + 255) / 256, 256, 0, stream>>>(src, dst, E, cursor, eidx);

    dim3 ggrid((NN + 127) / 128);  // 782, single column pass (BN=256)
    // layer 1: H1 = ns.(X @ W1)  (scale in epilogue)
    k_mfgemm<true><<<ggrid, 512, 0, stream>>>(features, norm_src, Wf1, Hbf);
    k_spmm_bf<<<(NN + 3) / 4, 256, 0, stream>>>(Hbf, rowptr, eidx, norm_dst,
                                                norm_src, b1, Xbf, out, 1);
    // layer 2
    k_mfgemm<false><<<ggrid, 512, 0, stream>>>(Xbf, nullptr, Wf2, Hbf);
    k_spmm_bf<<<(NN + 3) / 4, 256, 0, stream>>>(Hbf, rowptr, eidx, norm_dst,
                                                norm_src, b2, nullptr, out, 0);
}